// Round 17
// baseline (571.186 us; speedup 1.0000x reference)
//
#include <hip/hip_runtime.h>
#include <cstdint>
#include <type_traits>

typedef uint16_t u16;
typedef uint32_t u32;
typedef __attribute__((ext_vector_type(4))) float f32x4;
typedef __attribute__((ext_vector_type(8))) __bf16 vbf8;
typedef __attribute__((ext_vector_type(8))) short vs8;

// ---- MFMA operand-type hedge: prefer v8bf16, fall back to v8i16 ----
template <typename T, typename = void>
struct CanMfma : std::false_type {};
template <typename T>
struct CanMfma<T, std::void_t<decltype(__builtin_amdgcn_mfma_f32_16x16x32_bf16(
    std::declval<T>(), std::declval<T>(), std::declval<f32x4>(), 0, 0, 0))>>
    : std::true_type {};
typedef std::conditional_t<CanMfma<vbf8>::value, vbf8, vs8> frag_t;

__device__ __forceinline__ f32x4 mfma_bf16(frag_t a, frag_t b, f32x4 c) {
  return __builtin_amdgcn_mfma_f32_16x16x32_bf16(a, b, c, 0, 0, 0);
}

__device__ __forceinline__ u16 f2bf(float f) {
  u32 u = __builtin_bit_cast(u32, f);
  u32 r = (u + 0x7FFFu + ((u >> 16) & 1u)) >> 16;
  return (u16)r;
}

__device__ __forceinline__ void gload_lds16(const void* g, void* l) {
  __builtin_amdgcn_global_load_lds(
      (const __attribute__((address_space(1))) void*)g,
      (__attribute__((address_space(3))) void*)l, 16, 0, 0);
}

#define SB0() __builtin_amdgcn_sched_barrier(0)

// ---------------- merged prep: cast_x + cast_p + 4 weight transposes ----------------
__device__ __forceinline__ void transpose_body(
    const float* __restrict__ in, u16* __restrict__ out, int K, int N,
    int k0, int n0, float (*tile)[33]) {
  const int tr = threadIdx.x >> 5, tc = threadIdx.x & 31;
#pragma unroll
  for (int i = 0; i < 4; ++i)
    tile[tr + i * 8][tc] = in[(size_t)(k0 + tr + i * 8) * N + (n0 + tc)];
  __syncthreads();
#pragma unroll
  for (int i = 0; i < 4; ++i)
    out[(size_t)(n0 + tr + i * 8) * K + (k0 + tc)] = f2bf(tile[tc][tr + i * 8]);
}

__global__ __launch_bounds__(256) void prep_kernel(
    const float* __restrict__ x, const float* __restrict__ p,
    const float* __restrict__ Wq, const float* __restrict__ Ww,
    const float* __restrict__ Wk, const float* __restrict__ Wv,
    u16* __restrict__ x_bf, u16* __restrict__ p_bf,
    u16* __restrict__ wq_t, u16* __restrict__ ww_t, u16* __restrict__ wkv_t) {
  __shared__ float tile[32][33];
  const int bid = blockIdx.x;
  if (bid < 32768) {
    const size_t i = (size_t)bid * 256 + threadIdx.x;
    const float4 a  = ((const float4*)x)[i * 2];
    const float4 b2 = ((const float4*)x)[i * 2 + 1];
    uint4 o;
    o.x = (u32)f2bf(a.x)  | ((u32)f2bf(a.y)  << 16);
    o.y = (u32)f2bf(a.z)  | ((u32)f2bf(a.w)  << 16);
    o.z = (u32)f2bf(b2.x) | ((u32)f2bf(b2.y) << 16);
    o.w = (u32)f2bf(b2.z) | ((u32)f2bf(b2.w) << 16);
    ((uint4*)x_bf)[i] = o;
  } else if (bid < 33076) {
    const int i = (bid - 32768) * 256 + threadIdx.x;
    if (i < 78848) {
      const float4 a  = ((const float4*)p)[(size_t)i * 2];
      const float4 b2 = ((const float4*)p)[(size_t)i * 2 + 1];
      uint4 o;
      o.x = (u32)f2bf(a.x)  | ((u32)f2bf(a.y)  << 16);
      o.y = (u32)f2bf(a.z)  | ((u32)f2bf(a.w)  << 16);
      o.z = (u32)f2bf(b2.x) | ((u32)f2bf(b2.y) << 16);
      o.w = (u32)f2bf(b2.z) | ((u32)f2bf(b2.w) << 16);
      ((uint4*)p_bf)[(size_t)i] = o;
    }
  } else if (bid < 35124) {
    const bool isQ = bid < 34100;
    const int r = (bid - (isQ ? 33076 : 34100));
    transpose_body(isQ ? Wq : Ww, isQ ? wq_t : ww_t, 1024, 1024,
                   (r & 31) * 32, (r >> 5) * 32, tile);
  } else {
    const bool isK = bid < 35636;
    const int r = (bid - (isK ? 35124 : 35636));
    transpose_body(isK ? Wk : Wv, isK ? wkv_t : (wkv_t + 1024 * 512), 512, 1024,
                   (r & 15) * 32, (r >> 4) * 32, tile);
  }
}

// ---------------- small GEMM (128^2, 2-phase dbuf): merged K/V projection ------------
template <bool OUT_BF16>
__global__ __launch_bounds__(256) void gemm_bt(
    const u16* __restrict__ A, const u16* __restrict__ Bt,
    const float* __restrict__ biasA, const float* __restrict__ biasB,
    void* __restrict__ Cout,
    int M, int N, int K, int Mtiles, int Ntiles) {
  __shared__ char Al[2][128 * 32 * 2];
  __shared__ char Bl[2][128 * 32 * 2];

  const int nwg = Mtiles * Ntiles;
  int bid = (int)blockIdx.x;
  bid = (bid & 7) * (nwg >> 3) + (bid >> 3);
  const int mt = bid / Ntiles, nt = bid % Ntiles;
  const int m0 = mt * 128, n0 = nt * 128;

  const int tid = (int)threadIdx.x;
  const int lane = tid & 63;
  const int wv = tid >> 6;
  const int wm = wv & 1, wn = wv >> 1;
  const int lr = lane & 15, lg = lane >> 4;
  const int rsub = lane >> 2;
  const int slot = lane & 3;
  const int rb0 = n0 + rsub;

  auto stage = [&](int buf, int t) {
    const int k0 = t << 5;
#pragma unroll
    for (int c = 0; c < 2; ++c) {
      const int ci = c * 4 + wv;
      int rra = m0 + ci * 16 + rsub;
      if (rra >= M) rra = M - 1;
      gload_lds16(A + (size_t)rra * K + k0 + slot * 8, Al[buf] + ci * 1024);
      const int rrb = rb0 + ci * 16;
      gload_lds16(Bt + (size_t)rrb * K + k0 + slot * 8, Bl[buf] + ci * 1024);
    }
  };

  f32x4 zero4 = {0.f, 0.f, 0.f, 0.f};
  f32x4 acc[4][4];
#pragma unroll
  for (int i = 0; i < 4; ++i)
#pragma unroll
    for (int j = 0; j < 4; ++j) acc[i][j] = zero4;

  const int nk = K >> 5;
  int cur = 0;
  stage(0, 0);
  __syncthreads();

  for (int t = 0; t < nk; ++t) {
    if (t + 1 < nk) stage(cur ^ 1, t + 1);
    frag_t af[4], bf[4];
#pragma unroll
    for (int i = 0; i < 4; ++i) {
      af[i] = *(const frag_t*)(Al[cur] + (wm * 64 + i * 16 + lr) * 64 + lg * 16);
      bf[i] = *(const frag_t*)(Bl[cur] + (wn * 64 + i * 16 + lr) * 64 + lg * 16);
    }
#pragma unroll
    for (int i = 0; i < 4; ++i)
#pragma unroll
      for (int j = 0; j < 4; ++j)
        acc[i][j] = mfma_bf16(af[i], bf[j], acc[i][j]);
    __syncthreads();
    cur ^= 1;
  }

#pragma unroll
  for (int j = 0; j < 4; ++j) {
    const int col = n0 + wn * 64 + j * 16 + lr;
    const float bv = (col < 1024) ? biasA[col] : biasB[col - 1024];
#pragma unroll
    for (int i = 0; i < 4; ++i) {
      const int rbase = m0 + wm * 64 + i * 16 + lg * 4;
#pragma unroll
      for (int r = 0; r < 4; ++r) {
        const int row = rbase + r;
        const float val = acc[i][j][r] + bv;
        if constexpr (OUT_BF16) {
          u32 me = f2bf(val);
          u32 other = __shfl_xor(me, 1);
          if ((lane & 1) == 0 && row < M) {
            *(u32*)((u16*)Cout + (size_t)row * N + col) = me | (other << 16);
          }
        } else {
          if (row < M) ((float*)Cout)[(size_t)row * N + col] = val;
        }
      }
    }
  }
}

// ---------------- 8-phase GEMM (proven R15/R16): 256^2, BK=64, 8 waves (2Mx4N) ------
template <bool OUT_BF16>
__global__ __launch_bounds__(512, 1) void gemm8p(
    const u16* __restrict__ A, const u16* __restrict__ Bt,
    const float* __restrict__ bias, void* __restrict__ Cout,
    int M, int N, int K) {
  __shared__ u16 Al[2][256 * 64];
  __shared__ u16 Bl[2][256 * 64];

  const int Ntiles = N >> 8;
  const int nwg = (M >> 8) * Ntiles;
  int bid = (int)blockIdx.x;
  bid = (bid & 7) * (nwg >> 3) + (bid >> 3);
  const int mt = bid / Ntiles, ntl = bid % Ntiles;
  const int m0 = mt << 8, n0 = ntl << 8;

  const int tid = (int)threadIdx.x;
  const int lane = tid & 63;
  const int wid = tid >> 6;
  const int wm = wid >> 2, wn = wid & 3;
  const int lr = lane & 15, lg = lane >> 4;
  const int sslot = (lane & 7) ^ (lane >> 3);
  const int lrow = lane >> 3;

  auto stageA = [&](u16* dst, int half, int t) {
#pragma unroll
    for (int sub = 0; sub < 2; ++sub) {
      const int s = half + sub * 2;
      const u16* g = A + (size_t)(m0 + s * 64 + wid * 8 + lrow) * K + t * 64 + sslot * 8;
      u16* l = dst + (s & 1) * 8192 + (s >> 1) * 4096 + wid * 512;
      gload_lds16(g, l);
    }
  };
  auto stageB = [&](u16* dst, int half, int t) {
#pragma unroll
    for (int sub = 0; sub < 2; ++sub) {
      const int ub = wid * 16 + sub * 8;
      const int r = n0 + (ub >> 5) * 64 + half * 32 + (ub & 31) + lrow;
      const u16* g = Bt + (size_t)r * K + t * 64 + sslot * 8;
      u16* l = dst + half * 8192 + ub * 64;
      gload_lds16(g, l);
    }
  };

  auto ldsA = [&](const u16* base, int r, int ks) -> frag_t {
    const int off = ((r >> 6) & 1) * 8192 + (r >> 7) * 4096 + (r & 63) * 64 +
                    ((((ks) << 2) + lg) ^ (r & 7)) * 8;
    return *(const frag_t*)(base + off);
  };
  auto ldsB = [&](const u16* base, int r, int ks) -> frag_t {
    const int off = ((r >> 5) & 1) * 8192 + (r >> 6) * 2048 + (r & 31) * 64 +
                    ((((ks) << 2) + lg) ^ (r & 7)) * 8;
    return *(const frag_t*)(base + off);
  };

  f32x4 acc[8][4];
#pragma unroll
  for (int i = 0; i < 8; ++i)
#pragma unroll
    for (int j = 0; j < 4; ++j)
#pragma unroll
      for (int r = 0; r < 4; ++r) acc[i][j][r] = 0.f;

  frag_t aR[4][2], b0R[2][2], b1R[2][2];
  auto mmq = [&](frag_t (&bb)[2][2], int mo, int no) {
    __builtin_amdgcn_s_setprio(1);
#pragma unroll
    for (int i = 0; i < 4; ++i)
#pragma unroll
      for (int j = 0; j < 2; ++j) {
        acc[mo + i][no + j] = mfma_bf16(aR[i][0], bb[j][0], acc[mo + i][no + j]);
        acc[mo + i][no + j] = mfma_bf16(aR[i][1], bb[j][1], acc[mo + i][no + j]);
      }
    __builtin_amdgcn_s_setprio(0);
  };

  const int nt = K >> 6;
  const int arow = wm * 128 + lr;
  const int brow = wn * 64 + lr;

  stageA(&Al[0][0], 0, 0); stageA(&Al[0][0], 1, 0);
  stageB(&Bl[0][0], 0, 0); stageB(&Bl[0][0], 1, 0);
  stageA(&Al[1][0], 0, 1);
  stageB(&Bl[1][0], 0, 1); stageB(&Bl[1][0], 1, 1);
  asm volatile("s_waitcnt vmcnt(6)" ::: "memory");
  __builtin_amdgcn_s_barrier();

  for (int t = 0; t < nt; ++t) {
    const int cur = t & 1;
    const u16* bA = &Al[cur][0];
    const u16* bB = &Bl[cur][0];
#pragma unroll
    for (int i = 0; i < 4; ++i) {
      aR[i][0] = ldsA(bA, arow + i * 16, 0);
      aR[i][1] = ldsA(bA, arow + i * 16, 1);
    }
#pragma unroll
    for (int j = 0; j < 2; ++j) {
      b0R[j][0] = ldsB(bB, brow + j * 16, 0);
      b0R[j][1] = ldsB(bB, brow + j * 16, 1);
    }
    if (t + 1 < nt) stageA(&Al[cur ^ 1][0], 1, t + 1);
    asm volatile("s_waitcnt lgkmcnt(8)" ::: "memory");
    SB0();
    __builtin_amdgcn_s_barrier();
    asm volatile("s_waitcnt lgkmcnt(0)" ::: "memory");
    SB0();
    mmq(b0R, 0, 0);
    __builtin_amdgcn_s_barrier();
#pragma unroll
    for (int j = 0; j < 2; ++j) {
      b1R[j][0] = ldsB(bB, brow + 32 + j * 16, 0);
      b1R[j][1] = ldsB(bB, brow + 32 + j * 16, 1);
    }
    if (t + 2 < nt) stageA(&Al[cur][0], 0, t + 2);
    SB0();
    __builtin_amdgcn_s_barrier();
    asm volatile("s_waitcnt lgkmcnt(0)" ::: "memory");
    SB0();
    mmq(b1R, 0, 2);
    __builtin_amdgcn_s_barrier();
#pragma unroll
    for (int i = 0; i < 4; ++i) {
      aR[i][0] = ldsA(bA, arow + 64 + i * 16, 0);
      aR[i][1] = ldsA(bA, arow + 64 + i * 16, 1);
    }
    if (t + 2 < nt) stageB(&Bl[cur][0], 0, t + 2);
    SB0();
    __builtin_amdgcn_s_barrier();
    asm volatile("s_waitcnt lgkmcnt(0)" ::: "memory");
    SB0();
    mmq(b1R, 4, 2);
    __builtin_amdgcn_s_barrier();
    if (t + 2 < nt) stageB(&Bl[cur][0], 1, t + 2);
    mmq(b0R, 4, 0);
    if (t + 2 < nt)
      asm volatile("s_waitcnt vmcnt(6)" ::: "memory");
    else if (t + 1 < nt)
      asm volatile("s_waitcnt vmcnt(0)" ::: "memory");
    if (t + 1 < nt) __builtin_amdgcn_s_barrier();
  }

  float bvv[4];
#pragma unroll
  for (int nf = 0; nf < 4; ++nf) bvv[nf] = bias[n0 + wn * 64 + nf * 16 + lr];
#pragma unroll
  for (int mf = 0; mf < 8; ++mf) {
    const int rbase = m0 + wm * 128 + mf * 16 + lg * 4;
#pragma unroll
    for (int rr = 0; rr < 4; ++rr) {
      const int row = rbase + rr;
#pragma unroll
      for (int nf = 0; nf < 4; ++nf) {
        const int cb = n0 + wn * 64 + nf * 16;
        const float val = acc[mf][nf][rr] + bvv[nf];
        if constexpr (OUT_BF16) {
          u32 me = f2bf(val);
          u32 d0 = me | (__shfl_xor(me, 1) << 16);
          u32 d1 = __shfl_xor(d0, 2);
          if ((lane & 3) == 0) {
            uint2 o; o.x = d0; o.y = d1;
            *(uint2*)((u16*)Cout + (size_t)row * N + cb + (lr & 12)) = o;
          }
        } else {
          float v0 = val;
          float v1 = __shfl_xor(v0, 1);
          float v2 = __shfl_xor(v0, 2);
          float v3 = __shfl_xor(v1, 2);
          if ((lane & 3) == 0) {
            float4 o; o.x = v0; o.y = v1; o.z = v2; o.w = v3;
            *(float4*)((float*)Cout + (size_t)row * N + cb + (lr & 12)) = o;
          }
        }
      }
    }
  }
}

// ---------------- FUSED: 8-phase Q-projection + attention ---------------------------
// GEMM part identical to gemm8p. After the K-loop: LDS repurposed as per-head
// K[4][96][72] + Vt[4][64][104] (verified attn staging) + wave-private Q strips
// Qw[8][32][64] (slot^(row&7) swizzle both sides). Each wave's acc sub-tile
// (128 q-rows x 1 full head) is attended in 4 sub-passes of 32 rows; O -> Oout.
__global__ __launch_bounds__(512, 1) void gemm8p_fa(
    const u16* __restrict__ A, const u16* __restrict__ Bt,
    const float* __restrict__ bias, const u16* __restrict__ KV,
    u16* __restrict__ Oout, int M, int N, int K) {
  __shared__ u16 smem[70656];  // 141312 B
  u16* Al0 = smem;             // [2][16384]
  u16* Bl0 = smem + 32768;

  const int Ntiles = N >> 8;
  const int nwg = (M >> 8) * Ntiles;
  int bid = (int)blockIdx.x;
  bid = (bid & 7) * (nwg >> 3) + (bid >> 3);
  const int mt = bid / Ntiles, ntl = bid % Ntiles;
  const int m0 = mt << 8, n0 = ntl << 8;

  const int tid = (int)threadIdx.x;
  const int lane = tid & 63;
  const int wid = tid >> 6;
  const int wm = wid >> 2, wn = wid & 3;
  const int lr = lane & 15, lg = lane >> 4;
  const int sslot = (lane & 7) ^ (lane >> 3);
  const int lrow = lane >> 3;

  auto stageA = [&](u16* dst, int half, int t) {
#pragma unroll
    for (int sub = 0; sub < 2; ++sub) {
      const int s = half + sub * 2;
      const u16* g = A + (size_t)(m0 + s * 64 + wid * 8 + lrow) * K + t * 64 + sslot * 8;
      u16* l = dst + (s & 1) * 8192 + (s >> 1) * 4096 + wid * 512;
      gload_lds16(g, l);
    }
  };
  auto stageB = [&](u16* dst, int half, int t) {
#pragma unroll
    for (int sub = 0; sub < 2; ++sub) {
      const int ub = wid * 16 + sub * 8;
      const int r = n0 + (ub >> 5) * 64 + half * 32 + (ub & 31) + lrow;
      const u16* g = Bt + (size_t)r * K + t * 64 + sslot * 8;
      u16* l = dst + half * 8192 + ub * 64;
      gload_lds16(g, l);
    }
  };
  auto ldsA = [&](const u16* base, int r, int ks) -> frag_t {
    const int off = ((r >> 6) & 1) * 8192 + (r >> 7) * 4096 + (r & 63) * 64 +
                    ((((ks) << 2) + lg) ^ (r & 7)) * 8;
    return *(const frag_t*)(base + off);
  };
  auto ldsB = [&](const u16* base, int r, int ks) -> frag_t {
    const int off = ((r >> 5) & 1) * 8192 + (r >> 6) * 2048 + (r & 31) * 64 +
                    ((((ks) << 2) + lg) ^ (r & 7)) * 8;
    return *(const frag_t*)(base + off);
  };

  f32x4 acc[8][4];
#pragma unroll
  for (int i = 0; i < 8; ++i)
#pragma unroll
    for (int j = 0; j < 4; ++j)
#pragma unroll
      for (int r = 0; r < 4; ++r) acc[i][j][r] = 0.f;

  frag_t aR[4][2], b0R[2][2], b1R[2][2];
  auto mmq = [&](frag_t (&bb)[2][2], int mo, int no) {
    __builtin_amdgcn_s_setprio(1);
#pragma unroll
    for (int i = 0; i < 4; ++i)
#pragma unroll
      for (int j = 0; j < 2; ++j) {
        acc[mo + i][no + j] = mfma_bf16(aR[i][0], bb[j][0], acc[mo + i][no + j]);
        acc[mo + i][no + j] = mfma_bf16(aR[i][1], bb[j][1], acc[mo + i][no + j]);
      }
    __builtin_amdgcn_s_setprio(0);
  };

  const int nt = K >> 6;
  const int arow = wm * 128 + lr;
  const int brow = wn * 64 + lr;

  stageA(Al0, 0, 0); stageA(Al0, 1, 0);
  stageB(Bl0, 0, 0); stageB(Bl0, 1, 0);
  stageA(Al0 + 16384, 0, 1);
  stageB(Bl0 + 16384, 0, 1); stageB(Bl0 + 16384, 1, 1);
  asm volatile("s_waitcnt vmcnt(6)" ::: "memory");
  __builtin_amdgcn_s_barrier();

  for (int t = 0; t < nt; ++t) {
    const int cur = t & 1;
    const u16* bA = Al0 + cur * 16384;
    const u16* bB = Bl0 + cur * 16384;
#pragma unroll
    for (int i = 0; i < 4; ++i) {
      aR[i][0] = ldsA(bA, arow + i * 16, 0);
      aR[i][1] = ldsA(bA, arow + i * 16, 1);
    }
#pragma unroll
    for (int j = 0; j < 2; ++j) {
      b0R[j][0] = ldsB(bB, brow + j * 16, 0);
      b0R[j][1] = ldsB(bB, brow + j * 16, 1);
    }
    if (t + 1 < nt) stageA(Al0 + (cur ^ 1) * 16384, 1, t + 1);
    asm volatile("s_waitcnt lgkmcnt(8)" ::: "memory");
    SB0();
    __builtin_amdgcn_s_barrier();
    asm volatile("s_waitcnt lgkmcnt(0)" ::: "memory");
    SB0();
    mmq(b0R, 0, 0);
    __builtin_amdgcn_s_barrier();
#pragma unroll
    for (int j = 0; j < 2; ++j) {
      b1R[j][0] = ldsB(bB, brow + 32 + j * 16, 0);
      b1R[j][1] = ldsB(bB, brow + 32 + j * 16, 1);
    }
    if (t + 2 < nt) stageA(Al0 + cur * 16384, 0, t + 2);
    SB0();
    __builtin_amdgcn_s_barrier();
    asm volatile("s_waitcnt lgkmcnt(0)" ::: "memory");
    SB0();
    mmq(b1R, 0, 2);
    __builtin_amdgcn_s_barrier();
#pragma unroll
    for (int i = 0; i < 4; ++i) {
      aR[i][0] = ldsA(bA, arow + 64 + i * 16, 0);
      aR[i][1] = ldsA(bA, arow + 64 + i * 16, 1);
    }
    if (t + 2 < nt) stageB(Bl0 + cur * 16384, 0, t + 2);
    SB0();
    __builtin_amdgcn_s_barrier();
    asm volatile("s_waitcnt lgkmcnt(0)" ::: "memory");
    SB0();
    mmq(b1R, 4, 2);
    __builtin_amdgcn_s_barrier();
    if (t + 2 < nt) stageB(Bl0 + cur * 16384, 1, t + 2);
    mmq(b0R, 4, 0);
    if (t + 2 < nt)
      asm volatile("s_waitcnt vmcnt(6)" ::: "memory");
    else if (t + 1 < nt)
      asm volatile("s_waitcnt vmcnt(0)" ::: "memory");
    if (t + 1 < nt) __builtin_amdgcn_s_barrier();
  }

  __syncthreads();  // all waves done with GEMM LDS

  // ---- repurpose LDS ----
  u16* Kl4 = smem;                  // 4 x [96][72]  = 27648 u16
  u16* Vt4 = smem + 27648;          // 4 x [64][104] = 26624 u16
  u16* Qw  = smem + 27648 + 26624;  // 8 x [32][64]  = 16384 u16

  const int b = m0 >> 12;
  const int hbase = n0 >> 6;
  // cooperative K/V staging: 2 squads of 256 threads, 2 heads each (verified code)
  {
    const int sq = tid >> 8;
    const int t2 = tid & 255;
#pragma unroll
    for (int hh = 0; hh < 2; ++hh) {
      const int hl = sq * 2 + hh;
      const int hg = hbase + hl;
      u16* KlH = Kl4 + hl * 6912;
      u16* VtH = Vt4 + hl * 6656;
#pragma unroll
      for (int it = 0; it < 3; ++it) {
        const int idx = t2 + it * 256;
        const int key = idx >> 3, s = idx & 7;
        uint4 val{0u, 0u, 0u, 0u};
        if (key < 77)
          val = *(const uint4*)(KV + ((size_t)(b * 77 + key)) * 2048 + hg * 64 + s * 8);
        *(uint4*)(KlH + key * 72 + s * 8) = val;
      }
#pragma unroll
      for (int it = 0; it < 3; ++it) {
        const int idx = t2 + it * 256;
        if (idx < 616) {
          const int key = idx >> 3, s = idx & 7;
          const uint4 v4 = *(const uint4*)(KV + ((size_t)(b * 77 + key)) * 2048 +
                                           1024 + hg * 64 + s * 8);
          const u16* e = (const u16*)&v4;
#pragma unroll
          for (int j = 0; j < 8; ++j) VtH[(s * 8 + j) * 104 + key] = e[j];
        }
      }
#pragma unroll
      for (int it = 0; it < 5; ++it) {
        const int idx = t2 + it * 256;
        if (idx < 1216) {
          const int d = idx / 19, kk = 77 + idx % 19;
          VtH[d * 104 + kk] = 0;
        }
      }
    }
  }
  __syncthreads();  // K/V published

  // ---- per-wave attention: head = hbase + wn, q-rows = m0 + wm*128 + [0,128) ----
  const u16* KlH = Kl4 + wn * 6912;
  const u16* VtH = Vt4 + wn * 6656;
  u16* QwW = Qw + wid * 2048;  // [32][64]
  const int qbase = (m0 & 4095) + wm * 128;
  const int hg = hbase + wn;
  float bvv[4];
#pragma unroll
  for (int nf = 0; nf < 4; ++nf) bvv[nf] = bias[hg * 64 + nf * 16 + lr];
  f32x4 zero4 = {0.f, 0.f, 0.f, 0.f};

#pragma unroll
  for (int sub = 0; sub < 4; ++sub) {
    // write 32 rows of Q (acc + bias -> bf16 -> swizzled LDS strip, wave-private)
#pragma unroll
    for (int mm = 0; mm < 2; ++mm) {
      const int mf = sub * 2 + mm;
#pragma unroll
      for (int rr = 0; rr < 4; ++rr) {
        const int r2 = mm * 16 + lg * 4 + rr;
#pragma unroll
        for (int nf = 0; nf < 4; ++nf) {
          const float val = acc[mf][nf][rr] + bvv[nf];
          u32 me = f2bf(val);
          u32 d0 = me | (__shfl_xor(me, 1) << 16);
          u32 d1 = __shfl_xor(d0, 2);
          u32 d2 = __shfl_xor(d0, 4);
          u32 d3 = __shfl_xor(d1, 4);
          if ((lane & 7) == 0) {
            const int s3 = nf * 2 + (lr >> 3);
            uint4 o; o.x = d0; o.y = d1; o.z = d2; o.w = d3;
            *(uint4*)(QwW + r2 * 64 + ((s3 ^ (r2 & 7)) * 8)) = o;
          }
        }
      }
    }
    asm volatile("s_waitcnt lgkmcnt(0)" ::: "memory");
    SB0();

#pragma unroll
    for (int g = 0; g < 2; ++g) {
      // Q frags from LDS strip (row = g*16 + lr)
      const int r2q = g * 16 + lr;
      frag_t qf[2];
#pragma unroll
      for (int ks = 0; ks < 2; ++ks)
        qf[ks] = *(const frag_t*)(QwW + r2q * 64 + (((ks * 4 + lg) ^ (r2q & 7)) * 8));

      f32x4 sa[5] = {zero4, zero4, zero4, zero4, zero4};
#pragma unroll
      for (int ks = 0; ks < 2; ++ks) {
#pragma unroll
        for (int kt = 0; kt < 5; ++kt) {
          frag_t kf = *(const frag_t*)(KlH + (kt * 16 + lr) * 72 + ks * 32 + lg * 8);
          sa[kt] = mfma_bf16(kf, qf[ks], sa[kt]);
        }
      }

      float p[5][4];
      float mx = -3.0e38f;
#pragma unroll
      for (int kt = 0; kt < 5; ++kt)
#pragma unroll
        for (int r = 0; r < 4; ++r) {
          const int key = kt * 16 + lg * 4 + r;
          float s = sa[kt][r] * 0.125f;
          if (key >= 77) s = -3.0e38f;
          p[kt][r] = s;
          mx = fmaxf(mx, s);
        }
      mx = fmaxf(mx, __shfl_xor(mx, 16));
      mx = fmaxf(mx, __shfl_xor(mx, 32));
      float sum = 0.f;
#pragma unroll
      for (int kt = 0; kt < 5; ++kt)
#pragma unroll
        for (int r = 0; r < 4; ++r) {
          const float e = __expf(p[kt][r] - mx);
          p[kt][r] = e;
          sum += e;
        }
      sum += __shfl_xor(sum, 16);
      sum += __shfl_xor(sum, 32);
      const float rden = 1.0f / sum;
#pragma unroll
      for (int kt = 0; kt < 5; ++kt)
#pragma unroll
        for (int r = 0; r < 4; ++r) p[kt][r] *= rden;

      union FP { frag_t v; u16 e[8]; };
      frag_t pa[3];
#pragma unroll
      for (int kb = 0; kb < 3; ++kb) {
        FP f;
#pragma unroll
        for (int j = 0; j < 8; ++j) {
          const int kt = 2 * kb + (j >> 2);
          f.e[j] = (kt < 5) ? f2bf(p[kt][j & 3]) : (u16)0;
        }
        pa[kb] = f.v;
      }

      f32x4 oa[4] = {zero4, zero4, zero4, zero4};
#pragma unroll
      for (int ot = 0; ot < 4; ++ot) {
        const int d = ot * 16 + lr;
#pragma unroll
        for (int kb = 0; kb < 3; ++kb) {
          const int key0 = kb * 32 + lg * 4;
          FP vb;
          *(uint2*)(&vb.e[0]) = *(const uint2*)(VtH + d * 104 + key0);
          *(uint2*)(&vb.e[4]) = *(const uint2*)(VtH + d * 104 + key0 + 16);
          oa[ot] = mfma_bf16(pa[kb], vb.v, oa[ot]);
        }
      }

#pragma unroll
      for (int ot = 0; ot < 4; ++ot)
#pragma unroll
        for (int r = 0; r < 4; ++r) {
          const int qr = qbase + sub * 32 + g * 16 + lg * 4 + r;
          u32 me = f2bf(oa[ot][r]);
          u32 other = __shfl_xor(me, 1);
          if ((lane & 1) == 0) {
            *(u32*)(Oout + ((size_t)(b * 4096 + qr)) * 1024 + hg * 64 +
                    ot * 16 + lr) = me | (other << 16);
          }
        }
    }
    asm volatile("s_waitcnt lgkmcnt(0)" ::: "memory");  // WAR: strip reuse next sub
    SB0();
  }
}

// ---------------- launch ----------------
extern "C" void kernel_launch(void* const* d_in, const int* in_sizes, int n_in,
                              void* d_out, int out_size, void* d_ws, size_t ws_size,
                              hipStream_t stream) {
  const float* x  = (const float*)d_in[0];
  const float* p  = (const float*)d_in[1];
  const float* Wq = (const float*)d_in[2];
  const float* bq = (const float*)d_in[3];
  const float* Wk = (const float*)d_in[4];
  const float* bk = (const float*)d_in[5];
  const float* Wv = (const float*)d_in[6];
  const float* bv = (const float*)d_in[7];
  const float* Ww = (const float*)d_in[8];
  const float* bw = (const float*)d_in[9];

  char* ws = (char*)d_ws;
  if (ws_size < 281034752ULL) return;

  u16* x_bf  = (u16*)(ws + 0);          // 65536x1024 bf16 (input cast; read-only after)
  u16* ao_bf = (u16*)(ws + 134217728);  // 65536x1024 attn output (was q_bf)
  u16* wq_t  = (u16*)(ws + 268435456);  // [1024][1024]
  u16* ww_t  = (u16*)(ws + 270532608);  // [1024][1024]
  u16* wkv_t = (u16*)(ws + 272629760);  // [2048][512]
  u16* p_bf  = (u16*)(ws + 274726912);  // 1232x512
  u16* kv_bf = (u16*)(ws + 275988480);  // [1232][2048]

  prep_kernel<<<36148, 256, 0, stream>>>(x, p, Wq, Ww, Wk, Wv,
                                         x_bf, p_bf, wq_t, ww_t, wkv_t);
  gemm_bt<true><<<160, 256, 0, stream>>>(p_bf, wkv_t, bk, bv, kv_bf,
                                         1232, 2048, 512, 10, 16);
  // fused Q-projection + attention -> ao_bf
  gemm8p_fa<<<1024, 512, 0, stream>>>(x_bf, wq_t, bq, kv_bf, ao_bf,
                                      65536, 1024, 1024);
  // out projection: 8-phase kernel, fp32 epilogue
  gemm8p<false><<<1024, 512, 0, stream>>>(ao_bf, ww_t, bw, d_out, 65536, 1024, 1024);
}

// Round 18
// 514.580 us; speedup vs baseline: 1.1100x; 1.1100x over previous
//
#include <hip/hip_runtime.h>
#include <cstdint>
#include <type_traits>

typedef uint16_t u16;
typedef uint32_t u32;
typedef __attribute__((ext_vector_type(4))) float f32x4;
typedef __attribute__((ext_vector_type(8))) __bf16 vbf8;
typedef __attribute__((ext_vector_type(8))) short vs8;

// ---- MFMA operand-type hedge: prefer v8bf16, fall back to v8i16 ----
template <typename T, typename = void>
struct CanMfma : std::false_type {};
template <typename T>
struct CanMfma<T, std::void_t<decltype(__builtin_amdgcn_mfma_f32_16x16x32_bf16(
    std::declval<T>(), std::declval<T>(), std::declval<f32x4>(), 0, 0, 0))>>
    : std::true_type {};
typedef std::conditional_t<CanMfma<vbf8>::value, vbf8, vs8> frag_t;

__device__ __forceinline__ f32x4 mfma_bf16(frag_t a, frag_t b, f32x4 c) {
  return __builtin_amdgcn_mfma_f32_16x16x32_bf16(a, b, c, 0, 0, 0);
}

__device__ __forceinline__ u16 f2bf(float f) {
  u32 u = __builtin_bit_cast(u32, f);
  u32 r = (u + 0x7FFFu + ((u >> 16) & 1u)) >> 16;
  return (u16)r;
}

__device__ __forceinline__ void gload_lds16(const void* g, void* l) {
  __builtin_amdgcn_global_load_lds(
      (const __attribute__((address_space(1))) void*)g,
      (__attribute__((address_space(3))) void*)l, 16, 0, 0);
}

#define SB0() __builtin_amdgcn_sched_barrier(0)

// ---------------- merged prep: cast_x + cast_p + 4 weight transposes ----------------
__device__ __forceinline__ void transpose_body(
    const float* __restrict__ in, u16* __restrict__ out, int K, int N,
    int k0, int n0, float (*tile)[33]) {
  const int tr = threadIdx.x >> 5, tc = threadIdx.x & 31;
#pragma unroll
  for (int i = 0; i < 4; ++i)
    tile[tr + i * 8][tc] = in[(size_t)(k0 + tr + i * 8) * N + (n0 + tc)];
  __syncthreads();
#pragma unroll
  for (int i = 0; i < 4; ++i)
    out[(size_t)(n0 + tr + i * 8) * K + (k0 + tc)] = f2bf(tile[tc][tr + i * 8]);
}

__global__ __launch_bounds__(256) void prep_kernel(
    const float* __restrict__ x, const float* __restrict__ p,
    const float* __restrict__ Wq, const float* __restrict__ Ww,
    const float* __restrict__ Wk, const float* __restrict__ Wv,
    u16* __restrict__ x_bf, u16* __restrict__ p_bf,
    u16* __restrict__ wq_t, u16* __restrict__ ww_t, u16* __restrict__ wkv_t) {
  __shared__ float tile[32][33];
  const int bid = blockIdx.x;
  if (bid < 32768) {
    const size_t i = (size_t)bid * 256 + threadIdx.x;
    const float4 a  = ((const float4*)x)[i * 2];
    const float4 b2 = ((const float4*)x)[i * 2 + 1];
    uint4 o;
    o.x = (u32)f2bf(a.x)  | ((u32)f2bf(a.y)  << 16);
    o.y = (u32)f2bf(a.z)  | ((u32)f2bf(a.w)  << 16);
    o.z = (u32)f2bf(b2.x) | ((u32)f2bf(b2.y) << 16);
    o.w = (u32)f2bf(b2.z) | ((u32)f2bf(b2.w) << 16);
    ((uint4*)x_bf)[i] = o;
  } else if (bid < 33076) {
    const int i = (bid - 32768) * 256 + threadIdx.x;
    if (i < 78848) {
      const float4 a  = ((const float4*)p)[(size_t)i * 2];
      const float4 b2 = ((const float4*)p)[(size_t)i * 2 + 1];
      uint4 o;
      o.x = (u32)f2bf(a.x)  | ((u32)f2bf(a.y)  << 16);
      o.y = (u32)f2bf(a.z)  | ((u32)f2bf(a.w)  << 16);
      o.z = (u32)f2bf(b2.x) | ((u32)f2bf(b2.y) << 16);
      o.w = (u32)f2bf(b2.z) | ((u32)f2bf(b2.w) << 16);
      ((uint4*)p_bf)[(size_t)i] = o;
    }
  } else if (bid < 35124) {
    const bool isQ = bid < 34100;
    const int r = (bid - (isQ ? 33076 : 34100));
    transpose_body(isQ ? Wq : Ww, isQ ? wq_t : ww_t, 1024, 1024,
                   (r & 31) * 32, (r >> 5) * 32, tile);
  } else {
    const bool isK = bid < 35636;
    const int r = (bid - (isK ? 35124 : 35636));
    transpose_body(isK ? Wk : Wv, isK ? wkv_t : (wkv_t + 1024 * 512), 512, 1024,
                   (r & 15) * 32, (r >> 4) * 32, tile);
  }
}

// ---------------- small GEMM (128^2, 2-phase dbuf): merged K/V projection ------------
template <bool OUT_BF16>
__global__ __launch_bounds__(256) void gemm_bt(
    const u16* __restrict__ A, const u16* __restrict__ Bt,
    const float* __restrict__ biasA, const float* __restrict__ biasB,
    void* __restrict__ Cout,
    int M, int N, int K, int Mtiles, int Ntiles) {
  __shared__ char Al[2][128 * 32 * 2];
  __shared__ char Bl[2][128 * 32 * 2];

  const int nwg = Mtiles * Ntiles;
  int bid = (int)blockIdx.x;
  bid = (bid & 7) * (nwg >> 3) + (bid >> 3);
  const int mt = bid / Ntiles, nt = bid % Ntiles;
  const int m0 = mt * 128, n0 = nt * 128;

  const int tid = (int)threadIdx.x;
  const int lane = tid & 63;
  const int wv = tid >> 6;
  const int wm = wv & 1, wn = wv >> 1;
  const int lr = lane & 15, lg = lane >> 4;
  const int rsub = lane >> 2;
  const int slot = lane & 3;
  const int rb0 = n0 + rsub;

  auto stage = [&](int buf, int t) {
    const int k0 = t << 5;
#pragma unroll
    for (int c = 0; c < 2; ++c) {
      const int ci = c * 4 + wv;
      int rra = m0 + ci * 16 + rsub;
      if (rra >= M) rra = M - 1;
      gload_lds16(A + (size_t)rra * K + k0 + slot * 8, Al[buf] + ci * 1024);
      const int rrb = rb0 + ci * 16;
      gload_lds16(Bt + (size_t)rrb * K + k0 + slot * 8, Bl[buf] + ci * 1024);
    }
  };

  f32x4 zero4 = {0.f, 0.f, 0.f, 0.f};
  f32x4 acc[4][4];
#pragma unroll
  for (int i = 0; i < 4; ++i)
#pragma unroll
    for (int j = 0; j < 4; ++j) acc[i][j] = zero4;

  const int nk = K >> 5;
  int cur = 0;
  stage(0, 0);
  __syncthreads();

  for (int t = 0; t < nk; ++t) {
    if (t + 1 < nk) stage(cur ^ 1, t + 1);
    frag_t af[4], bf[4];
#pragma unroll
    for (int i = 0; i < 4; ++i) {
      af[i] = *(const frag_t*)(Al[cur] + (wm * 64 + i * 16 + lr) * 64 + lg * 16);
      bf[i] = *(const frag_t*)(Bl[cur] + (wn * 64 + i * 16 + lr) * 64 + lg * 16);
    }
#pragma unroll
    for (int i = 0; i < 4; ++i)
#pragma unroll
      for (int j = 0; j < 4; ++j)
        acc[i][j] = mfma_bf16(af[i], bf[j], acc[i][j]);
    __syncthreads();
    cur ^= 1;
  }

#pragma unroll
  for (int j = 0; j < 4; ++j) {
    const int col = n0 + wn * 64 + j * 16 + lr;
    const float bv = (col < 1024) ? biasA[col] : biasB[col - 1024];
#pragma unroll
    for (int i = 0; i < 4; ++i) {
      const int rbase = m0 + wm * 64 + i * 16 + lg * 4;
#pragma unroll
      for (int r = 0; r < 4; ++r) {
        const int row = rbase + r;
        const float val = acc[i][j][r] + bv;
        if constexpr (OUT_BF16) {
          u32 me = f2bf(val);
          u32 other = __shfl_xor(me, 1);
          if ((lane & 1) == 0 && row < M) {
            *(u32*)((u16*)Cout + (size_t)row * N + col) = me | (other << 16);
          }
        } else {
          if (row < M) ((float*)Cout)[(size_t)row * N + col] = val;
        }
      }
    }
  }
}

// ---------------- m201-faithful 8-phase GEMM: 256^2, BK=64, 8 waves (2Mx4N) ---------
// Derived ledger: A halves = 64-row stripes, half=(r>>6)&1 (Ah0 read P0, Ah1 P2);
// B halves = 32-row stripes, half=(r>>5)&1 (Bh0 read P0, Bh1 P1). Stage stream
// (1 half/phase, 3-half lead): tau.P0: Ah1(tau+1); P1: Ah0(tau+2); P2: Bh0(tau+2);
// P3: Bh1(tau+2). vmcnt(6) ONLY at P3. Verified R15/R16: ~210us per 65536x1024x1024.
template <bool OUT_BF16>
__global__ __launch_bounds__(512, 1) void gemm8p(
    const u16* __restrict__ A, const u16* __restrict__ Bt,
    const float* __restrict__ bias, void* __restrict__ Cout,
    int M, int N, int K) {
  __shared__ u16 Al[2][256 * 64];
  __shared__ u16 Bl[2][256 * 64];

  const int Ntiles = N >> 8;
  const int nwg = (M >> 8) * Ntiles;
  int bid = (int)blockIdx.x;
  bid = (bid & 7) * (nwg >> 3) + (bid >> 3);  // bijective: nwg % 8 == 0
  const int mt = bid / Ntiles, ntl = bid % Ntiles;
  const int m0 = mt << 8, n0 = ntl << 8;

  const int tid = (int)threadIdx.x;
  const int lane = tid & 63;
  const int wid = tid >> 6;
  const int wm = wid >> 2, wn = wid & 3;  // 2M x 4N; per-wave out 128x64
  const int lr = lane & 15, lg = lane >> 4;
  const int sslot = (lane & 7) ^ (lane >> 3);
  const int lrow = lane >> 3;

  auto stageA = [&](u16* dst, int half, int t) {
#pragma unroll
    for (int sub = 0; sub < 2; ++sub) {
      const int s = half + sub * 2;
      const u16* g = A + (size_t)(m0 + s * 64 + wid * 8 + lrow) * K + t * 64 + sslot * 8;
      u16* l = dst + (s & 1) * 8192 + (s >> 1) * 4096 + wid * 512;
      gload_lds16(g, l);
    }
  };
  auto stageB = [&](u16* dst, int half, int t) {
#pragma unroll
    for (int sub = 0; sub < 2; ++sub) {
      const int ub = wid * 16 + sub * 8;
      const int r = n0 + (ub >> 5) * 64 + half * 32 + (ub & 31) + lrow;
      const u16* g = Bt + (size_t)r * K + t * 64 + sslot * 8;
      u16* l = dst + half * 8192 + ub * 64;
      gload_lds16(g, l);
    }
  };

  auto ldsA = [&](const u16* base, int r, int ks) -> frag_t {
    const int off = ((r >> 6) & 1) * 8192 + (r >> 7) * 4096 + (r & 63) * 64 +
                    ((((ks) << 2) + lg) ^ (r & 7)) * 8;
    return *(const frag_t*)(base + off);
  };
  auto ldsB = [&](const u16* base, int r, int ks) -> frag_t {
    const int off = ((r >> 5) & 1) * 8192 + (r >> 6) * 2048 + (r & 31) * 64 +
                    ((((ks) << 2) + lg) ^ (r & 7)) * 8;
    return *(const frag_t*)(base + off);
  };

  f32x4 acc[8][4];
#pragma unroll
  for (int i = 0; i < 8; ++i)
#pragma unroll
    for (int j = 0; j < 4; ++j)
#pragma unroll
      for (int r = 0; r < 4; ++r) acc[i][j][r] = 0.f;

  frag_t aR[4][2], b0R[2][2], b1R[2][2];
  auto mmq = [&](frag_t (&bb)[2][2], int mo, int no) {
    __builtin_amdgcn_s_setprio(1);
#pragma unroll
    for (int i = 0; i < 4; ++i)
#pragma unroll
      for (int j = 0; j < 2; ++j) {
        acc[mo + i][no + j] = mfma_bf16(aR[i][0], bb[j][0], acc[mo + i][no + j]);
        acc[mo + i][no + j] = mfma_bf16(aR[i][1], bb[j][1], acc[mo + i][no + j]);
      }
    __builtin_amdgcn_s_setprio(0);
  };

  const int nt = K >> 6;  // >= 3
  const int arow = wm * 128 + lr;
  const int brow = wn * 64 + lr;

  // prologue: tile0 all 4 halves; tile1's Ah0, Bh0, Bh1; vmcnt(6) -> tile0 landed
  stageA(&Al[0][0], 0, 0); stageA(&Al[0][0], 1, 0);
  stageB(&Bl[0][0], 0, 0); stageB(&Bl[0][0], 1, 0);
  stageA(&Al[1][0], 0, 1);
  stageB(&Bl[1][0], 0, 1); stageB(&Bl[1][0], 1, 1);
  asm volatile("s_waitcnt vmcnt(6)" ::: "memory");
  __builtin_amdgcn_s_barrier();

  for (int t = 0; t < nt; ++t) {
    const int cur = t & 1;
    const u16* bA = &Al[cur][0];
    const u16* bB = &Bl[cur][0];
    // ---- P0: read a(mf0-3) + b0 (12 reads); stage Ah1(t+1) -> other buf
#pragma unroll
    for (int i = 0; i < 4; ++i) {
      aR[i][0] = ldsA(bA, arow + i * 16, 0);
      aR[i][1] = ldsA(bA, arow + i * 16, 1);
    }
#pragma unroll
    for (int j = 0; j < 2; ++j) {
      b0R[j][0] = ldsB(bB, brow + j * 16, 0);
      b0R[j][1] = ldsB(bB, brow + j * 16, 1);
    }
    if (t + 1 < nt) stageA(&Al[cur ^ 1][0], 1, t + 1);
    asm volatile("s_waitcnt lgkmcnt(8)" ::: "memory");
    SB0();
    __builtin_amdgcn_s_barrier();
    asm volatile("s_waitcnt lgkmcnt(0)" ::: "memory");
    SB0();
    mmq(b0R, 0, 0);
    __builtin_amdgcn_s_barrier();
    // ---- P1: read b1 (4); stage Ah0(t+2) -> current buf
#pragma unroll
    for (int j = 0; j < 2; ++j) {
      b1R[j][0] = ldsB(bB, brow + 32 + j * 16, 0);
      b1R[j][1] = ldsB(bB, brow + 32 + j * 16, 1);
    }
    if (t + 2 < nt) stageA(&Al[cur][0], 0, t + 2);
    SB0();
    __builtin_amdgcn_s_barrier();
    asm volatile("s_waitcnt lgkmcnt(0)" ::: "memory");
    SB0();
    mmq(b1R, 0, 2);
    __builtin_amdgcn_s_barrier();
    // ---- P2: read a(mf4-7) (8); stage Bh0(t+2)
#pragma unroll
    for (int i = 0; i < 4; ++i) {
      aR[i][0] = ldsA(bA, arow + 64 + i * 16, 0);
      aR[i][1] = ldsA(bA, arow + 64 + i * 16, 1);
    }
    if (t + 2 < nt) stageB(&Bl[cur][0], 0, t + 2);
    SB0();
    __builtin_amdgcn_s_barrier();
    asm volatile("s_waitcnt lgkmcnt(0)" ::: "memory");
    SB0();
    mmq(b1R, 4, 2);
    __builtin_amdgcn_s_barrier();
    // ---- P3: no reads; stage Bh1(t+2); MFMA; counted drain (never 0 mid-loop)
    if (t + 2 < nt) stageB(&Bl[cur][0], 1, t + 2);
    mmq(b0R, 4, 0);
    if (t + 2 < nt)
      asm volatile("s_waitcnt vmcnt(6)" ::: "memory");
    else if (t + 1 < nt)
      asm volatile("s_waitcnt vmcnt(0)" ::: "memory");
    if (t + 1 < nt) __builtin_amdgcn_s_barrier();
  }

  // epilogue: row = m0+wm*128+mf*16+lg*4+rr ; col = n0+wn*64+nf*16+lr
  float bvv[4];
#pragma unroll
  for (int nf = 0; nf < 4; ++nf) bvv[nf] = bias[n0 + wn * 64 + nf * 16 + lr];
#pragma unroll
  for (int mf = 0; mf < 8; ++mf) {
    const int rbase = m0 + wm * 128 + mf * 16 + lg * 4;
#pragma unroll
    for (int rr = 0; rr < 4; ++rr) {
      const int row = rbase + rr;
#pragma unroll
      for (int nf = 0; nf < 4; ++nf) {
        const int cb = n0 + wn * 64 + nf * 16;
        const float val = acc[mf][nf][rr] + bvv[nf];
        if constexpr (OUT_BF16) {
          u32 me = f2bf(val);
          u32 d0 = me | (__shfl_xor(me, 1) << 16);
          u32 d1 = __shfl_xor(d0, 2);
          if ((lane & 3) == 0) {
            uint2 o; o.x = d0; o.y = d1;
            *(uint2*)((u16*)Cout + (size_t)row * N + cb + (lr & 12)) = o;
          }
        } else {
          float v0 = val;
          float v1 = __shfl_xor(v0, 1);
          float v2 = __shfl_xor(v0, 2);
          float v3 = __shfl_xor(v1, 2);
          if ((lane & 3) == 0) {
            float4 o; o.x = v0; o.y = v1; o.z = v2; o.w = v3;
            *(float4*)((float*)Cout + (size_t)row * N + cb + (lr & 12)) = o;
          }
        }
      }
    }
  }
}

// ---------------- attention: 4 q-tiles per block; K/V from merged [1232][2048] ------
__global__ __launch_bounds__(256) void attn_kernel(
    const u16* __restrict__ Q, const u16* __restrict__ KV,
    u16* __restrict__ O) {
  __shared__ u16 Kl[96][72];
  __shared__ u16 Vt[64][104];

  const int bid = blockIdx.x;
  const int qt0 = bid & 15;
  const int h = (bid >> 4) & 15;
  const int b = bid >> 8;
  const int tid = threadIdx.x;

#pragma unroll
  for (int it = 0; it < 3; ++it) {
    const int idx = tid + it * 256;
    const int key = idx >> 3, s = idx & 7;
    uint4 val{0u, 0u, 0u, 0u};
    if (key < 77)
      val = *(const uint4*)(KV + ((size_t)(b * 77 + key)) * 2048 + h * 64 + s * 8);
    *(uint4*)(&Kl[key][s * 8]) = val;
  }
#pragma unroll
  for (int it = 0; it < 3; ++it) {
    const int idx = tid + it * 256;
    if (idx < 616) {
      const int key = idx >> 3, s = idx & 7;
      const uint4 v4 = *(const uint4*)(KV + ((size_t)(b * 77 + key)) * 2048 +
                                       1024 + h * 64 + s * 8);
      const u16* e = (const u16*)&v4;
#pragma unroll
      for (int j = 0; j < 8; ++j) Vt[s * 8 + j][key] = e[j];
    }
  }
#pragma unroll
  for (int it = 0; it < 5; ++it) {
    const int idx = tid + it * 256;
    if (idx < 1216) {
      const int d = idx / 19, kk = 77 + idx % 19;
      Vt[d][kk] = 0;
    }
  }
  __syncthreads();

  const int lane = tid & 63;
  const int wv = tid >> 6;
  const int lr = lane & 15;
  const int lg = lane >> 4;
  f32x4 zero4 = {0.f, 0.f, 0.f, 0.f};

  for (int q4 = 0; q4 < 4; ++q4) {
    const int qt = qt0 * 4 + q4;

    const size_t qrow = (size_t)(b * 4096 + qt * 64 + wv * 16 + lr) * 1024 + h * 64;
    frag_t qf[2];
#pragma unroll
    for (int ks = 0; ks < 2; ++ks)
      qf[ks] = *(const frag_t*)(Q + qrow + ks * 32 + lg * 8);

    f32x4 sa[5] = {zero4, zero4, zero4, zero4, zero4};
#pragma unroll
    for (int ks = 0; ks < 2; ++ks) {
#pragma unroll
      for (int kt = 0; kt < 5; ++kt) {
        frag_t kf = *(const frag_t*)(&Kl[kt * 16 + lr][ks * 32 + lg * 8]);
        sa[kt] = mfma_bf16(kf, qf[ks], sa[kt]);
      }
    }

    float p[5][4];
    float mx = -3.0e38f;
#pragma unroll
    for (int kt = 0; kt < 5; ++kt)
#pragma unroll
      for (int r = 0; r < 4; ++r) {
        const int key = kt * 16 + lg * 4 + r;
        float s = sa[kt][r] * 0.125f;
        if (key >= 77) s = -3.0e38f;
        p[kt][r] = s;
        mx = fmaxf(mx, s);
      }
    mx = fmaxf(mx, __shfl_xor(mx, 16));
    mx = fmaxf(mx, __shfl_xor(mx, 32));
    float sum = 0.f;
#pragma unroll
    for (int kt = 0; kt < 5; ++kt)
#pragma unroll
      for (int r = 0; r < 4; ++r) {
        const float e = __expf(p[kt][r] - mx);
        p[kt][r] = e;
        sum += e;
      }
    sum += __shfl_xor(sum, 16);
    sum += __shfl_xor(sum, 32);
    const float rden = 1.0f / sum;
#pragma unroll
    for (int kt = 0; kt < 5; ++kt)
#pragma unroll
      for (int r = 0; r < 4; ++r) p[kt][r] *= rden;

    union FP { frag_t v; u16 e[8]; };
    frag_t pa[3];
#pragma unroll
    for (int kb = 0; kb < 3; ++kb) {
      FP f;
#pragma unroll
      for (int j = 0; j < 8; ++j) {
        const int kt = 2 * kb + (j >> 2);
        f.e[j] = (kt < 5) ? f2bf(p[kt][j & 3]) : (u16)0;
      }
      pa[kb] = f.v;
    }

    f32x4 oa[4] = {zero4, zero4, zero4, zero4};
#pragma unroll
    for (int nt = 0; nt < 4; ++nt) {
      const int d = nt * 16 + lr;
#pragma unroll
      for (int kb = 0; kb < 3; ++kb) {
        const int key0 = kb * 32 + lg * 4;
        FP vb;
        *(uint2*)(&vb.e[0]) = *(const uint2*)(&Vt[d][key0]);
        *(uint2*)(&vb.e[4]) = *(const uint2*)(&Vt[d][key0 + 16]);
        oa[nt] = mfma_bf16(pa[kb], vb.v, oa[nt]);
      }
    }

#pragma unroll
    for (int nt = 0; nt < 4; ++nt)
#pragma unroll
      for (int r = 0; r < 4; ++r) {
        const int qr = wv * 16 + lg * 4 + r;
        u32 me = f2bf(oa[nt][r]);
        u32 other = __shfl_xor(me, 1);
        if ((lane & 1) == 0) {
          *(u32*)(O + ((size_t)(b * 4096 + qt * 64 + qr)) * 1024 + h * 64 +
                  nt * 16 + lr) = me | (other << 16);
        }
      }
  }
}

// ---------------- launch ----------------
extern "C" void kernel_launch(void* const* d_in, const int* in_sizes, int n_in,
                              void* d_out, int out_size, void* d_ws, size_t ws_size,
                              hipStream_t stream) {
  const float* x  = (const float*)d_in[0];
  const float* p  = (const float*)d_in[1];
  const float* Wq = (const float*)d_in[2];
  const float* bq = (const float*)d_in[3];
  const float* Wk = (const float*)d_in[4];
  const float* bk = (const float*)d_in[5];
  const float* Wv = (const float*)d_in[6];
  const float* bv = (const float*)d_in[7];
  const float* Ww = (const float*)d_in[8];
  const float* bw = (const float*)d_in[9];

  char* ws = (char*)d_ws;
  if (ws_size < 281034752ULL) return;

  u16* x_bf  = (u16*)(ws + 0);          // 65536x1024 bf16; reused as attn_out
  u16* q_bf  = (u16*)(ws + 134217728);  // 65536x1024
  u16* wq_t  = (u16*)(ws + 268435456);  // [1024][1024]
  u16* ww_t  = (u16*)(ws + 270532608);  // [1024][1024]
  u16* wkv_t = (u16*)(ws + 272629760);  // [2048][512]
  u16* p_bf  = (u16*)(ws + 274726912);  // 1232x512
  u16* kv_bf = (u16*)(ws + 275988480);  // [1232][2048]

  prep_kernel<<<36148, 256, 0, stream>>>(x, p, Wq, Ww, Wk, Wv,
                                         x_bf, p_bf, wq_t, ww_t, wkv_t);
  gemm_bt<true><<<160, 256, 0, stream>>>(p_bf, wkv_t, bk, bv, kv_bf,
                                         1232, 2048, 512, 10, 16);
  // Q projection: 8-phase kernel (proven R15)
  gemm8p<true><<<1024, 512, 0, stream>>>(x_bf, wq_t, bq, q_bf, 65536, 1024, 1024);
  attn_kernel<<<4096, 256, 0, stream>>>(q_bf, kv_bf, x_bf);
  // out projection: 8-phase kernel (same shape; fp32 epilogue)
  gemm8p<false><<<1024, 512, 0, stream>>>(x_bf, ww_t, bw, d_out, 65536, 1024, 1024);
}